// Round 4
// baseline (1116.277 us; speedup 1.0000x reference)
//
#include <hip/hip_runtime.h>

// CovariantEvolutionBlock on MI355X (gfx950).
// I/O is float32 (bf16-grid values); internal compute bf16 MFMA + fp32 accum.
// B=2, L=2048, D=1024, H=16, HD=64, N=B*L=4096 tokens.

typedef unsigned short u16;
typedef __attribute__((ext_vector_type(8))) short short8;
typedef __attribute__((ext_vector_type(4))) float f32x4;
typedef __attribute__((ext_vector_type(4))) unsigned short us4;

__device__ __forceinline__ float b2f(u16 u) {
    union { unsigned u; float f; } c; c.u = ((unsigned)u) << 16; return c.f;
}
__device__ __forceinline__ u16 f2b(float f) {
    union { float f; unsigned u; } c; c.f = f;
    unsigned x = c.u;
    unsigned r = (x + 0x7fffu + ((x >> 16) & 1u)) >> 16;   // RNE
    return (u16)r;
}

__device__ __forceinline__ void async_copy16(const u16* g, u16* l) {
    __builtin_amdgcn_global_load_lds(
        (const __attribute__((address_space(1))) unsigned int*)(g),
        (__attribute__((address_space(3))) unsigned int*)(l), 16, 0, 0);
}

// ---------------------------------------------------------------------------
// fp32 -> bf16 conversion, 4 elems/thread. n must be a multiple of 1024.
__global__ __launch_bounds__(256) void cvt_k(const float* __restrict__ s,
                                             u16* __restrict__ d, int n) {
    int i = (blockIdx.x * 256 + threadIdx.x) * 4;
    if (i >= n) return;
    float4 v = *(const float4*)(s + i);
    d[i + 0] = f2b(v.x); d[i + 1] = f2b(v.y);
    d[i + 2] = f2b(v.z); d[i + 3] = f2b(v.w);
}

// ---------------------------------------------------------------------------
// RMSNorm from fp32 input: one block per token, D=1024, 256 threads x 4.
__global__ __launch_bounds__(256) void rmsf_k(const float* __restrict__ x,
                                              const float* __restrict__ w,
                                              u16* __restrict__ y, int D) {
    int n = blockIdx.x;
    const float* xr = x + (size_t)n * D;
    float v[4]; float s = 0.f;
#pragma unroll
    for (int i = 0; i < 4; i++) {
        int idx = threadIdx.x + (i << 8);
        float f = xr[idx]; v[i] = f; s += f * f;
    }
#pragma unroll
    for (int m = 32; m >= 1; m >>= 1) s += __shfl_xor(s, m, 64);
    __shared__ float red[4];
    if ((threadIdx.x & 63) == 0) red[threadIdx.x >> 6] = s;
    __syncthreads();
    float tot = red[0] + red[1] + red[2] + red[3];
    float scale = rsqrtf(tot / (float)D + 1e-6f);
    u16* yr = y + (size_t)n * D;
#pragma unroll
    for (int i = 0; i < 4; i++) {
        int idx = threadIdx.x + (i << 8);
        yr[idx] = f2b(v[i] * scale * w[idx]);
    }
}

// RMSNorm from bf16 (internal) input.
__global__ __launch_bounds__(256) void rmsb_k(const u16* __restrict__ x,
                                              const float* __restrict__ w,
                                              u16* __restrict__ y, int D) {
    int n = blockIdx.x;
    const u16* xr = x + (size_t)n * D;
    float v[4]; float s = 0.f;
#pragma unroll
    for (int i = 0; i < 4; i++) {
        int idx = threadIdx.x + (i << 8);
        float f = b2f(xr[idx]); v[i] = f; s += f * f;
    }
#pragma unroll
    for (int m = 32; m >= 1; m >>= 1) s += __shfl_xor(s, m, 64);
    __shared__ float red[4];
    if ((threadIdx.x & 63) == 0) red[threadIdx.x >> 6] = s;
    __syncthreads();
    float tot = red[0] + red[1] + red[2] + red[3];
    float scale = rsqrtf(tot / (float)D + 1e-6f);
    u16* yr = y + (size_t)n * D;
#pragma unroll
    for (int i = 0; i < 4; i++) {
        int idx = threadIdx.x + (i << 8);
        yr[idx] = f2b(v[i] * scale * w[idx]);
    }
}

// ---------------------------------------------------------------------------
// Tiled NT GEMM: C[n,o] = act(sum_k A[n,k]*W[o,k] + bias[o]).
// 128x128 block tile, BK=32, 4 waves x (64x64), global_load_lds staging,
// LDS double-buffer (one barrier per K-iter). XOR-swizzled k-groups so
// ds_read_b128 fragment reads are ~2-way-per-bank (free).
// act: 0=none 1=silu 2=tanh. grid = (O/128, M/128).
// mode: 0 = row-major C[row*O+col]; 1 = per-head transpose for attention V:
//       C is VT[((b*16+h)*64 + d)*2048 + tok]  (B=2,H=16,HD=64,L=2048).
__global__ __launch_bounds__(256) void gemm_tile(const u16* __restrict__ A,
                                                 const u16* __restrict__ W,
                                                 const float* __restrict__ bias,
                                                 u16* __restrict__ C,
                                                 int K, int O, int act, int mode) {
    __shared__ u16 Asm[2][128 * 32];
    __shared__ u16 Bsm[2][128 * 32];

    const int tid = threadIdx.x;
    const int wid = tid >> 6, lane = tid & 63;
    const int l15 = lane & 15, quad = lane >> 4;
    const int row0 = blockIdx.y * 128, col0 = blockIdx.x * 128;
    const int wm = (wid >> 1) << 6, wn = (wid & 1) << 6;

    // Staging: thread serves rows sr and sr+64, 16B k-group (sc ^ swz(row)).
    const int sr = tid >> 2;
    const int sc = tid & 3;
    const int ga = sc ^ ((sr ^ (sr >> 2)) & 3);   // swz depends on r&15 only
    const u16* aS0 = A + (size_t)(row0 + sr) * K + ga * 8;
    const u16* aS1 = A + (size_t)(row0 + 64 + sr) * K + ga * 8;
    const u16* bS0 = W + (size_t)(col0 + sr) * K + ga * 8;
    const u16* bS1 = W + (size_t)(col0 + 64 + sr) * K + ga * 8;

    // Fragment-read k-group slot (row-within-16 = l15 for both A and B).
    const int qa = quad ^ ((l15 ^ (l15 >> 2)) & 3);

    f32x4 acc[4][4];
#pragma unroll
    for (int i = 0; i < 4; i++)
#pragma unroll
        for (int j = 0; j < 4; j++) acc[i][j] = (f32x4){0.f, 0.f, 0.f, 0.f};

    const int wbs = wid << 9;   // wave LDS base (elems): wid*64 lanes*8
    auto stage = [&](int buf, int kof) {
        async_copy16(aS0 + kof, &Asm[buf][wbs]);
        async_copy16(aS1 + kof, &Asm[buf][2048 + wbs]);
        async_copy16(bS0 + kof, &Bsm[buf][wbs]);
        async_copy16(bS1 + kof, &Bsm[buf][2048 + wbs]);
    };

    const int nk = K >> 5;
    stage(0, 0);
    __syncthreads();
    for (int kk = 0; kk < nk; kk++) {
        int cur = kk & 1;
        if (kk + 1 < nk) stage(1 - cur, (kk + 1) << 5);
        const u16* Ab = Asm[cur];
        const u16* Bb = Bsm[cur];
        short8 af[4], bf[4];
#pragma unroll
        for (int i = 0; i < 4; i++) {
            af[i] = *(const short8*)&Ab[(wm + i * 16 + l15) * 32 + qa * 8];
            bf[i] = *(const short8*)&Bb[(wn + i * 16 + l15) * 32 + qa * 8];
        }
#pragma unroll
        for (int i = 0; i < 4; i++)
#pragma unroll
            for (int j = 0; j < 4; j++)
                acc[i][j] = __builtin_amdgcn_mfma_f32_16x16x32_bf16(af[i], bf[j], acc[i][j], 0, 0, 0);
        __syncthreads();   // drains prefetch (vmcnt0) + guards buf reuse
    }

    if (mode == 0) {
#pragma unroll
        for (int j = 0; j < 4; j++) {
            int col = col0 + wn + j * 16 + l15;
            float bb = bias ? bias[col] : 0.f;
#pragma unroll
            for (int i = 0; i < 4; i++) {
                int rowb = row0 + wm + i * 16 + (quad << 2);
#pragma unroll
                for (int g = 0; g < 4; g++) {
                    float v = acc[i][j][g] + bb;
                    if (act == 1)      v = v / (1.f + __expf(-v));   // silu
                    else if (act == 2) v = tanhf(v);
                    C[(size_t)(rowb + g) * O + col] = f2b(v);
                }
            }
        }
    } else {
        // V-transpose epilogue: acc[i][j][g] is (tok=rowb+g, dim-col).
        // 4 consecutive toks -> one 8B store into VT[bh][d][tok].
#pragma unroll
        for (int j = 0; j < 4; j++) {
            int col = col0 + wn + j * 16 + l15;     // h*64 + d
            int h = col >> 6, d = col & 63;
#pragma unroll
            for (int i = 0; i < 4; i++) {
                int rowb = row0 + wm + i * 16 + (quad << 2);
                int bb_ = rowb >> 11;               // batch
                int tok = rowb & 2047;
                us4 pk;
#pragma unroll
                for (int g = 0; g < 4; g++) pk[g] = f2b(acc[i][j][g]);
                *(us4*)&C[(size_t)(((bb_ << 4) + h) * 64 + d) * 2048 + tok] = pk;
            }
        }
    }
}

// ---------------------------------------------------------------------------
// Sigmoid attention v2 (flash-style; sigmoid has no cross-key coupling).
// Wave = 16 queries of one (b,h); V is consumed pre-transposed per head
// (VT[bh][64][L]) so PV B-fragments are contiguous 16B loads.
// P round-trips LDS with row stride 40 elems (16B-aligned rows, low-conflict).
__global__ __launch_bounds__(256) void attn_k(const u16* __restrict__ Q,
                                              const u16* __restrict__ Kb,
                                              const u16* __restrict__ VT,
                                              const float* __restrict__ temp_p,
                                              u16* __restrict__ Oa,
                                              int L, int H, int D) {
    __shared__ u16 plds[4][16 * 40];
    int w = threadIdx.x >> 6, lane = threadIdx.x & 63;
    int qt = blockIdx.x * 4 + w;
    int tilesPerHead = L >> 4;
    int bh = qt / tilesPerHead, lq = qt - bh * tilesPerHead;
    int b = bh / H, h = bh - b * H;
    int l15 = lane & 15, quad = lane >> 4;
    float scale = 0.125f * temp_p[0];   // HD^-0.5 * temp, HD=64

    size_t rowQ = (size_t)(b * L + lq * 16 + l15) * D + h * 64 + quad * 8;
    short8 aq0 = *(const short8*)(Q + rowQ);
    short8 aq1 = *(const short8*)(Q + rowQ + 32);
    const u16* Kbase = Kb + (size_t)(b * L) * D + h * 64;
    const u16* VTb   = VT + (size_t)bh * 64 * L;

    f32x4 acc[4];
#pragma unroll
    for (int i = 0; i < 4; i++) acc[i] = (f32x4){0.f, 0.f, 0.f, 0.f};
    float rs[4] = {0.f, 0.f, 0.f, 0.f};
    u16* P = plds[w];

    for (int mc = 0; mc < L; mc += 32) {
#pragma unroll
        for (int kt = 0; kt < 2; kt++) {
            const u16* kp = Kbase + (size_t)(mc + kt * 16 + l15) * D + quad * 8;
            short8 b0 = *(const short8*)(kp);
            short8 b1 = *(const short8*)(kp + 32);
            f32x4 s = (f32x4){0.f, 0.f, 0.f, 0.f};
            s = __builtin_amdgcn_mfma_f32_16x16x32_bf16(aq0, b0, s, 0, 0, 0);
            s = __builtin_amdgcn_mfma_f32_16x16x32_bf16(aq1, b1, s, 0, 0, 0);
#pragma unroll
            for (int g = 0; g < 4; g++) {
                float p = 1.f / (1.f + __expf(-s[g] * scale));
                rs[g] += p;
                P[(quad * 4 + g) * 40 + kt * 16 + l15] = f2b(p);
            }
        }
        short8 ap = *(const short8*)&P[l15 * 40 + quad * 8];
#pragma unroll
        for (int dt4 = 0; dt4 < 4; dt4++) {
            short8 bv = *(const short8*)&VTb[(size_t)(dt4 * 16 + l15) * L + mc + quad * 8];
            acc[dt4] = __builtin_amdgcn_mfma_f32_16x16x32_bf16(ap, bv, acc[dt4], 0, 0, 0);
        }
    }

#pragma unroll
    for (int g = 0; g < 4; g++) {
#pragma unroll
        for (int m = 1; m < 16; m <<= 1) rs[g] += __shfl_xor(rs[g], m, 64);
    }
    u16* orow = Oa + (size_t)(b * L + lq * 16) * D + h * 64;
#pragma unroll
    for (int g = 0; g < 4; g++) {
        float denom = fmaxf(rs[g], 1.0f);
        int row = quad * 4 + g;
#pragma unroll
        for (int dt4 = 0; dt4 < 4; dt4++)
            orow[(size_t)row * D + dt4 * 16 + l15] = f2b(acc[dt4][g] / denom);
    }
}

// ---------------------------------------------------------------------------
// Glue kernels.
__global__ void concat2_k(u16* __restrict__ dst, const u16* __restrict__ s0,
                          const u16* __restrict__ s1, int total) {
    int i = blockIdx.x * 256 + threadIdx.x;
    if (i >= total) return;
    int j = i & 1023;
    int t = i >> 10;
    int seg = t & 1;
    int n = t >> 1;
    const u16* s = seg ? s1 : s0;
    dst[i] = s[(size_t)n * 1024 + j];
}

// cu_in = concat([connection(fp32), z1(bf16), dz(bf16)], -1)
__global__ void cucat_k(u16* __restrict__ dst, const float* __restrict__ conn,
                        const u16* __restrict__ z1, const u16* __restrict__ dz,
                        int total) {
    int i = blockIdx.x * 256 + threadIdx.x;
    if (i >= total) return;
    int j = i & 1023;
    int t = i >> 10;
    int seg = t % 3;
    int n = t / 3;
    size_t src = (size_t)n * 1024 + j;
    dst[i] = (seg == 0) ? f2b(conn[src]) : (seg == 1 ? z1[src] : dz[src]);
}

__global__ void dz_k(u16* __restrict__ d, const u16* __restrict__ a,
                     const u16* __restrict__ b, const float* __restrict__ dtp, int n) {
    int i = blockIdx.x * 256 + threadIdx.x;
    if (i >= n) return;
    float dt = dtp[0];
    d[i] = f2b(dt * (b2f(a[i]) + b2f(b[i])));
}

// z1 = z(fp32) + dz(bf16) + ctx(bf16) -> bf16 internal
__global__ void z1_k(u16* __restrict__ d, const float* __restrict__ z,
                     const u16* __restrict__ dz, const u16* __restrict__ ctx, int n) {
    int i = blockIdx.x * 256 + threadIdx.x;
    if (i >= n) return;
    d[i] = f2b(z[i] + b2f(dz[i]) + b2f(ctx[i]));
}

// conn_new = connection(fp32) + delta(bf16) -> fp32 out
__global__ void connew_k(float* __restrict__ d, const float* __restrict__ conn,
                         const u16* __restrict__ delta, int n) {
    int i = blockIdx.x * 256 + threadIdx.x;
    if (i >= n) return;
    d[i] = conn[i] + b2f(delta[i]);
}

// z2 = z1(bf16) + mf(bf16) -> fp32 out
__global__ void z2_k(float* __restrict__ d, const u16* __restrict__ z1,
                     const u16* __restrict__ mf, int n) {
    int i = blockIdx.x * 256 + threadIdx.x;
    if (i >= n) return;
    d[i] = b2f(z1[i]) + b2f(mf[i]);
}

__global__ void copyf_k(float* __restrict__ d, const float* __restrict__ s, int n) {
    int i = (blockIdx.x * 256 + threadIdx.x) * 4;
    if (i >= n) return;
    *(float4*)(d + i) = *(const float4*)(s + i);
}

// ---------------------------------------------------------------------------
extern "C" void kernel_launch(void* const* d_in, const int* in_sizes, int n_in,
                              void* d_out, int out_size, void* d_ws, size_t ws_size,
                              hipStream_t stream) {
    const int B = 2, L = 2048, D = 1024, H = 16, N = B * L;
    const float* z      = (const float*)d_in[0];
    const float* conn   = (const float*)d_in[1];
    const float* w_z    = (const float*)d_in[2];
    const float* w_c    = (const float*)d_in[3];
    const float* w_mlp  = (const float*)d_in[4];
    const float* f_w1   = (const float*)d_in[5];
    const float* f_b1   = (const float*)d_in[6];
    const float* f_w2   = (const float*)d_in[7];
    const float* f_b2   = (const float*)d_in[8];
    const float* g_w1   = (const float*)d_in[9];
    const float* g_b1   = (const float*)d_in[10];
    const float* g_w2   = (const float*)d_in[11];
    const float* g_b2   = (const float*)d_in[12];
    const float* dt_p   = (const float*)d_in[13];
    const float* q_w    = (const float*)d_in[14];
    const float* k_w    = (const float*)d_in[15];
    const float* v_w    = (const float*)d_in[16];
    const float* o_w    = (const float*)d_in[17];
    const float* temp_p = (const float*)d_in[18];
    const float* cu_w1  = (const float*)d_in[19];
    const float* cu_b1  = (const float*)d_in[20];
    const float* cu_w2  = (const float*)d_in[21];
    const float* cu_b2  = (const float*)d_in[22];
    const float* m_w1   = (const float*)d_in[23];
    const float* m_b1   = (const float*)d_in[24];
    const float* m_w2   = (const float*)d_in[25];
    const float* m_b2   = (const float*)d_in[26];

    float* out = (float*)d_out;
    u16* ws  = (u16*)d_ws;
    const size_t U = (size_t)N * D;   // 4M elems

    // Activation slots (bf16), liveness-packed: peak slot index 8 (9 units).
    u16* zn    = ws + 0 * U;
    u16* cn    = ws + 1 * U;
    u16* h1    = ws + 2 * U;   // 2 units (2-3)
    u16* dzl   = ws + 4 * U;
    u16* gcat  = ws + 5 * U;   // 2 units (5-6)
    u16* gh    = ws + 7 * U;
    u16* corr  = ws + 5 * U;   // gcat dead
    u16* dz    = ws + 6 * U;
    u16* zc    = ws + 2 * U;   // 2 units (2-3), h1 dead
    u16* Qb    = ws + 4 * U;   // dzl dead
    u16* Kbuf  = ws + 5 * U;   // corr dead
    u16* VT    = ws + 7 * U;   // gh dead; VT[bh][64][L], 4M elems
    u16* attn  = ws + 8 * U;
    u16* ctx   = ws + 4 * U;   // Qb dead
    u16* z1    = ws + 5 * U;   // Kbuf dead
    u16* cu_in = ws + 0 * U;   // 3 units (0-2): zn,cn,zc dead
    u16* cu_h  = ws + 3 * U;   // 2 units (3-4): zc(3),ctx dead
    u16* delta = ws + 7 * U;   // VT dead
    u16* z1n   = ws + 0 * U;   // cu_in dead
    u16* mh    = ws + 1 * U;   // 4 units (1-4)
    u16* mf    = ws + 0 * U;   // z1n dead

    // bf16 weight copies after activation slots: 29M u16 elems.
    u16* wb = ws + 9 * U;
    u16* bf_w1  = wb + 0;                       // 2M
    u16* bf_w2  = wb + 2 * 1024 * 1024;         // 2M
    u16* bg_w1  = wb + 4 * 1024 * 1024;         // 2M
    u16* bg_w2  = wb + 6 * 1024 * 1024;         // 1M
    u16* bq_w   = wb + 7 * 1024 * 1024;         // 2M
    u16* bk_w   = wb + 9 * 1024 * 1024;         // 2M
    u16* bv_w   = wb + 11 * 1024 * 1024;        // 1M
    u16* bo_w   = wb + 12 * 1024 * 1024;        // 1M
    u16* bcu_w1 = wb + 13 * 1024 * 1024;        // 6M
    u16* bcu_w2 = wb + 19 * 1024 * 1024;        // 2M
    u16* bm_w1  = wb + 21 * 1024 * 1024;        // 4M
    u16* bm_w2  = wb + 25 * 1024 * 1024;        // 4M

    auto cvt = [&](const float* s, u16* d, int n) {
        cvt_k<<<n / 1024, 256, 0, stream>>>(s, d, n);
    };
    cvt(f_w1, bf_w1, 2 * D * D);   cvt(f_w2, bf_w2, 2 * D * D);
    cvt(g_w1, bg_w1, 2 * D * D);   cvt(g_w2, bg_w2, D * D);
    cvt(q_w, bq_w, 2 * D * D);     cvt(k_w, bk_w, 2 * D * D);
    cvt(v_w, bv_w, D * D);         cvt(o_w, bo_w, D * D);
    cvt(cu_w1, bcu_w1, 6 * D * D); cvt(cu_w2, bcu_w2, 2 * D * D);
    cvt(m_w1, bm_w1, 4 * D * D);   cvt(m_w2, bm_w2, 4 * D * D);

    const int EW = (N * D + 255) / 256;
    auto gemm = [&](const u16* A, const u16* W, const float* bias, u16* C,
                    int K, int O, int act, int mode = 0) {
        dim3 grid(O / 128, N / 128);
        gemm_tile<<<grid, 256, 0, stream>>>(A, W, bias, C, K, O, act, mode);
    };

    rmsf_k<<<N, 256, 0, stream>>>(z, w_z, zn, D);
    rmsf_k<<<N, 256, 0, stream>>>(conn, w_c, cn, D);

    gemm(zn, bf_w1, f_b1, h1, D, 2 * D, 1);                  // silu
    gemm(h1, bf_w2, f_b2, dzl, 2 * D, D, 0);
    concat2_k<<<(N * 2 * D + 255) / 256, 256, 0, stream>>>(gcat, cn, dzl, N * 2 * D);
    gemm(gcat, bg_w1, g_b1, gh, 2 * D, D, 2);                // tanh
    gemm(gh, bg_w2, g_b2, corr, D, D, 0);
    dz_k<<<EW, 256, 0, stream>>>(dz, dzl, corr, dt_p, N * D);

    concat2_k<<<(N * 2 * D + 255) / 256, 256, 0, stream>>>(zc, zn, cn, N * 2 * D);
    gemm(zc, bq_w, nullptr, Qb, 2 * D, D, 0);
    gemm(zc, bk_w, nullptr, Kbuf, 2 * D, D, 0);
    gemm(zn, bv_w, nullptr, VT, D, D, 0, 1);                 // V, transposed per head
    attn_k<<<(B * H * L / 16) / 4, 256, 0, stream>>>(Qb, Kbuf, VT, temp_p, attn, L, H, D);
    gemm(attn, bo_w, nullptr, ctx, D, D, 0);

    z1_k<<<EW, 256, 0, stream>>>(z1, z, dz, ctx, N * D);

    cucat_k<<<(N * 3 * D + 255) / 256, 256, 0, stream>>>(cu_in, conn, z1, dz, N * 3 * D);
    gemm(cu_in, bcu_w1, cu_b1, cu_h, 3 * D, 2 * D, 1);       // silu
    gemm(cu_h, bcu_w2, cu_b2, delta, 2 * D, D, 0);
    connew_k<<<EW, 256, 0, stream>>>(out + U, conn, delta, N * D);   // conn_new
    copyf_k<<<(N * D + 1023) / 1024, 256, 0, stream>>>(out + 2 * U, z, N * D); // z_before

    rmsb_k<<<N, 256, 0, stream>>>(z1, w_mlp, z1n, D);
    gemm(z1n, bm_w1, m_b1, mh, D, 4 * D, 1);                 // silu
    gemm(mh, bm_w2, m_b2, mf, 4 * D, D, 0);
    z2_k<<<EW, 256, 0, stream>>>(out, z1, mf, N * D);                // z2
}

// Round 5
// 1002.234 us; speedup vs baseline: 1.1138x; 1.1138x over previous
//
#include <hip/hip_runtime.h>

// CovariantEvolutionBlock on MI355X (gfx950).
// I/O is float32 (bf16-grid values); internal compute bf16 MFMA + fp32 accum.
// B=2, L=2048, D=1024, H=16, HD=64, N=B*L=4096 tokens.

typedef unsigned short u16;
typedef __attribute__((ext_vector_type(8))) short short8;
typedef __attribute__((ext_vector_type(4))) float f32x4;
typedef __attribute__((ext_vector_type(4))) unsigned short us4;

__device__ __forceinline__ float b2f(u16 u) {
    union { unsigned u; float f; } c; c.u = ((unsigned)u) << 16; return c.f;
}
__device__ __forceinline__ u16 f2b(float f) {
    union { float f; unsigned u; } c; c.f = f;
    unsigned x = c.u;
    unsigned r = (x + 0x7fffu + ((x >> 16) & 1u)) >> 16;   // RNE
    return (u16)r;
}

__device__ __forceinline__ void async_copy16(const u16* g, u16* l) {
    __builtin_amdgcn_global_load_lds(
        (const __attribute__((address_space(1))) unsigned int*)(g),
        (__attribute__((address_space(3))) unsigned int*)(l), 16, 0, 0);
}

// ---------------------------------------------------------------------------
// fp32 -> bf16 conversion, 4 elems/thread. n must be a multiple of 1024.
__global__ __launch_bounds__(256) void cvt_k(const float* __restrict__ s,
                                             u16* __restrict__ d, int n) {
    int i = (blockIdx.x * 256 + threadIdx.x) * 4;
    if (i >= n) return;
    float4 v = *(const float4*)(s + i);
    d[i + 0] = f2b(v.x); d[i + 1] = f2b(v.y);
    d[i + 2] = f2b(v.z); d[i + 3] = f2b(v.w);
}

// ---------------------------------------------------------------------------
// RMSNorm from fp32 input: one block per token, D=1024, 256 threads x 4.
__global__ __launch_bounds__(256) void rmsf_k(const float* __restrict__ x,
                                              const float* __restrict__ w,
                                              u16* __restrict__ y, int D) {
    int n = blockIdx.x;
    const float* xr = x + (size_t)n * D;
    float v[4]; float s = 0.f;
#pragma unroll
    for (int i = 0; i < 4; i++) {
        int idx = threadIdx.x + (i << 8);
        float f = xr[idx]; v[i] = f; s += f * f;
    }
#pragma unroll
    for (int m = 32; m >= 1; m >>= 1) s += __shfl_xor(s, m, 64);
    __shared__ float red[4];
    if ((threadIdx.x & 63) == 0) red[threadIdx.x >> 6] = s;
    __syncthreads();
    float tot = red[0] + red[1] + red[2] + red[3];
    float scale = rsqrtf(tot / (float)D + 1e-6f);
    u16* yr = y + (size_t)n * D;
#pragma unroll
    for (int i = 0; i < 4; i++) {
        int idx = threadIdx.x + (i << 8);
        yr[idx] = f2b(v[i] * scale * w[idx]);
    }
}

// RMSNorm from bf16 (internal) input.
__global__ __launch_bounds__(256) void rmsb_k(const u16* __restrict__ x,
                                              const float* __restrict__ w,
                                              u16* __restrict__ y, int D) {
    int n = blockIdx.x;
    const u16* xr = x + (size_t)n * D;
    float v[4]; float s = 0.f;
#pragma unroll
    for (int i = 0; i < 4; i++) {
        int idx = threadIdx.x + (i << 8);
        float f = b2f(xr[idx]); v[i] = f; s += f * f;
    }
#pragma unroll
    for (int m = 32; m >= 1; m >>= 1) s += __shfl_xor(s, m, 64);
    __shared__ float red[4];
    if ((threadIdx.x & 63) == 0) red[threadIdx.x >> 6] = s;
    __syncthreads();
    float tot = red[0] + red[1] + red[2] + red[3];
    float scale = rsqrtf(tot / (float)D + 1e-6f);
    u16* yr = y + (size_t)n * D;
#pragma unroll
    for (int i = 0; i < 4; i++) {
        int idx = threadIdx.x + (i << 8);
        yr[idx] = f2b(v[i] * scale * w[idx]);
    }
}

// ---------------------------------------------------------------------------
// Tiled NT GEMM: C[n,o] = act(sum_k A[n,k]*W[o,k] + bias[o]).
// 128x128 block tile, BK=32, 4 waves x (64x64), global_load_lds staging,
// LDS double-buffer (one barrier per K-iter). XOR-swizzled k-groups so
// ds_read_b128 fragment reads are ~2-way-per-bank (free).
// act: 0=none 1=silu 2=tanh. grid = (O/128, M/128).
// mode: 0 = row-major C[row*O+col]; 1 = per-head transpose for attention V:
//       C is VT[((b*16+h)*64 + d)*2048 + tok]  (B=2,H=16,HD=64,L=2048).
__global__ __launch_bounds__(256) void gemm_tile(const u16* __restrict__ A,
                                                 const u16* __restrict__ W,
                                                 const float* __restrict__ bias,
                                                 u16* __restrict__ C,
                                                 int K, int O, int act, int mode) {
    __shared__ u16 Asm[2][128 * 32];
    __shared__ u16 Bsm[2][128 * 32];

    const int tid = threadIdx.x;
    const int wid = tid >> 6, lane = tid & 63;
    const int l15 = lane & 15, quad = lane >> 4;
    const int row0 = blockIdx.y * 128, col0 = blockIdx.x * 128;
    const int wm = (wid >> 1) << 6, wn = (wid & 1) << 6;

    const int sr = tid >> 2;
    const int sc = tid & 3;
    const int ga = sc ^ ((sr ^ (sr >> 2)) & 3);
    const u16* aS0 = A + (size_t)(row0 + sr) * K + ga * 8;
    const u16* aS1 = A + (size_t)(row0 + 64 + sr) * K + ga * 8;
    const u16* bS0 = W + (size_t)(col0 + sr) * K + ga * 8;
    const u16* bS1 = W + (size_t)(col0 + 64 + sr) * K + ga * 8;

    const int qa = quad ^ ((l15 ^ (l15 >> 2)) & 3);

    f32x4 acc[4][4];
#pragma unroll
    for (int i = 0; i < 4; i++)
#pragma unroll
        for (int j = 0; j < 4; j++) acc[i][j] = (f32x4){0.f, 0.f, 0.f, 0.f};

    const int wbs = wid << 9;
    auto stage = [&](int buf, int kof) {
        async_copy16(aS0 + kof, &Asm[buf][wbs]);
        async_copy16(aS1 + kof, &Asm[buf][2048 + wbs]);
        async_copy16(bS0 + kof, &Bsm[buf][wbs]);
        async_copy16(bS1 + kof, &Bsm[buf][2048 + wbs]);
    };

    const int nk = K >> 5;
    stage(0, 0);
    __syncthreads();
    for (int kk = 0; kk < nk; kk++) {
        int cur = kk & 1;
        if (kk + 1 < nk) stage(1 - cur, (kk + 1) << 5);
        const u16* Ab = Asm[cur];
        const u16* Bb = Bsm[cur];
        short8 af[4], bf[4];
#pragma unroll
        for (int i = 0; i < 4; i++) {
            af[i] = *(const short8*)&Ab[(wm + i * 16 + l15) * 32 + qa * 8];
            bf[i] = *(const short8*)&Bb[(wn + i * 16 + l15) * 32 + qa * 8];
        }
#pragma unroll
        for (int i = 0; i < 4; i++)
#pragma unroll
            for (int j = 0; j < 4; j++)
                acc[i][j] = __builtin_amdgcn_mfma_f32_16x16x32_bf16(af[i], bf[j], acc[i][j], 0, 0, 0);
        __syncthreads();
    }

    if (mode == 0) {
#pragma unroll
        for (int j = 0; j < 4; j++) {
            int col = col0 + wn + j * 16 + l15;
            float bb = bias ? bias[col] : 0.f;
#pragma unroll
            for (int i = 0; i < 4; i++) {
                int rowb = row0 + wm + i * 16 + (quad << 2);
#pragma unroll
                for (int g = 0; g < 4; g++) {
                    float v = acc[i][j][g] + bb;
                    if (act == 1)      v = v / (1.f + __expf(-v));   // silu
                    else if (act == 2) v = tanhf(v);
                    C[(size_t)(rowb + g) * O + col] = f2b(v);
                }
            }
        }
    } else {
        // V-transpose epilogue: 4 consecutive toks -> one 8B store VT[bh][d][tok].
#pragma unroll
        for (int j = 0; j < 4; j++) {
            int col = col0 + wn + j * 16 + l15;     // h*64 + d
            int h = col >> 6, d = col & 63;
#pragma unroll
            for (int i = 0; i < 4; i++) {
                int rowb = row0 + wm + i * 16 + (quad << 2);
                int bb_ = rowb >> 11;               // batch
                int tok = rowb & 2047;
                us4 pk;
#pragma unroll
                for (int g = 0; g < 4; g++) pk[g] = f2b(acc[i][j][g]);
                *(us4*)&C[(size_t)(((bb_ << 4) + h) * 64 + d) * 2048 + tok] = pk;
            }
        }
    }
}

// ---------------------------------------------------------------------------
// Sigmoid attention v3: block-cooperative flash-style.
// Block = 256 thr = 4 waves = 128 queries of one (b,h); iterates 64-key tiles.
// K-tile (64 keys x 64d) and V-tile (64d x 64 keys, from VT) staged to LDS via
// global_load_lds (XOR-swizzled 16B groups), double-buffered, 1 barrier/iter.
// P (16q x 64key) round-trips per-wave LDS (stride 72) into A-operand layout.
__global__ __launch_bounds__(256) void attn_k(const u16* __restrict__ Q,
                                              const u16* __restrict__ Kb,
                                              const u16* __restrict__ VT,
                                              const float* __restrict__ temp_p,
                                              u16* __restrict__ Oa) {
    const int L = 2048, H = 16, D = 1024;
    __shared__ u16 Ks[2][64 * 64];
    __shared__ u16 Vs[2][64 * 64];
    __shared__ u16 plds[4][16 * 72];

    const int tid = threadIdx.x;
    const int w = tid >> 6, lane = tid & 63;
    const int l15 = lane & 15, quad = lane >> 4;
    const int bh = blockIdx.x >> 4;           // 16 blocks per (b,h)
    const int qb0 = (blockIdx.x & 15) << 7;   // 128 queries per block
    const int b = bh >> 4, h = bh & 15;
    const float scale = 0.125f * temp_p[0];   // HD^-0.5 * temp

    // Q fragments: 2 q-tiles x 2 dim-halves (k=32 each).
    short8 aq[2][2];
#pragma unroll
    for (int qt = 0; qt < 2; qt++) {
        size_t row = (size_t)(b * L + qb0 + w * 32 + qt * 16 + l15) * D + h * 64;
#pragma unroll
        for (int hf = 0; hf < 2; hf++)
            aq[qt][hf] = *(const short8*)(Q + row + hf * 32 + quad * 8);
    }

    const u16* Kbase = Kb + (size_t)(b * L) * D + h * 64;
    const u16* VTb   = VT + (size_t)bh * 64 * L;

    // Staging source pointers: slot i (0..511): row r=i>>3, slot-group gs=i&7,
    // source group gsrc = gs ^ (r&7). Thread covers i = tid and tid+256.
    const int i0 = tid, i1 = tid + 256;
    const int r0 = i0 >> 3, g0 = (i0 & 7) ^ (r0 & 7);
    const int r1 = i1 >> 3, g1 = (i1 & 7) ^ (r1 & 7);
    const u16* kS0 = Kbase + (size_t)r0 * D + g0 * 8;
    const u16* kS1 = Kbase + (size_t)r1 * D + g1 * 8;
    const u16* vS0 = VTb + (size_t)r0 * L + g0 * 8;
    const u16* vS1 = VTb + (size_t)r1 * L + g1 * 8;

    auto stage = [&](int buf, int mc) {
        // wave-uniform LDS bases; lanes fill base+lane*16B.
        async_copy16(kS0 + (size_t)mc * D, &Ks[buf][w << 9]);
        async_copy16(kS1 + (size_t)mc * D, &Ks[buf][2048 + (w << 9)]);
        async_copy16(vS0 + mc, &Vs[buf][w << 9]);
        async_copy16(vS1 + mc, &Vs[buf][2048 + (w << 9)]);
    };

    f32x4 acc[2][4];
#pragma unroll
    for (int i = 0; i < 2; i++)
#pragma unroll
        for (int j = 0; j < 4; j++) acc[i][j] = (f32x4){0.f, 0.f, 0.f, 0.f};
    float rs[2][4] = {{0.f,0.f,0.f,0.f},{0.f,0.f,0.f,0.f}};
    u16* P = plds[w];
    const int lsw = l15 & 7;   // read-side swizzle key

    stage(0, 0);
    __syncthreads();
    for (int it = 0; it < 32; it++) {
        int cur = it & 1;
        if (it < 31) stage(1 - cur, (it + 1) << 6);
        const u16* Kt = Ks[cur];
        const u16* Vt = Vs[cur];
#pragma unroll
        for (int qt = 0; qt < 2; qt++) {
#pragma unroll
            for (int ks = 0; ks < 4; ks++) {
                f32x4 s = (f32x4){0.f, 0.f, 0.f, 0.f};
#pragma unroll
                for (int hf = 0; hf < 2; hf++) {
                    int slot = ((ks * 16 + l15) * 8 + ((hf * 4 + quad) ^ lsw)) * 8;
                    short8 bk = *(const short8*)&Kt[slot];
                    s = __builtin_amdgcn_mfma_f32_16x16x32_bf16(aq[qt][hf], bk, s, 0, 0, 0);
                }
#pragma unroll
                for (int g = 0; g < 4; g++) {
                    float p = 1.f / (1.f + __expf(-s[g] * scale));
                    rs[qt][g] += p;
                    P[(quad * 4 + g) * 72 + ks * 16 + l15] = f2b(p);
                }
            }
#pragma unroll
            for (int kh = 0; kh < 2; kh++) {
                short8 ap = *(const short8*)&P[l15 * 72 + kh * 32 + quad * 8];
#pragma unroll
                for (int dt = 0; dt < 4; dt++) {
                    int slot = ((dt * 16 + l15) * 8 + ((kh * 4 + quad) ^ lsw)) * 8;
                    short8 bv = *(const short8*)&Vt[slot];
                    acc[qt][dt] = __builtin_amdgcn_mfma_f32_16x16x32_bf16(ap, bv, acc[qt][dt], 0, 0, 0);
                }
            }
        }
        __syncthreads();
    }

#pragma unroll
    for (int qt = 0; qt < 2; qt++)
#pragma unroll
        for (int g = 0; g < 4; g++) {
#pragma unroll
            for (int m = 1; m < 16; m <<= 1) rs[qt][g] += __shfl_xor(rs[qt][g], m, 64);
        }

#pragma unroll
    for (int qt = 0; qt < 2; qt++) {
        u16* orow = Oa + (size_t)(b * L + qb0 + w * 32 + qt * 16) * D + h * 64;
#pragma unroll
        for (int g = 0; g < 4; g++) {
            float denom = fmaxf(rs[qt][g], 1.0f);
            int row = quad * 4 + g;
#pragma unroll
            for (int dt = 0; dt < 4; dt++)
                orow[(size_t)row * D + dt * 16 + l15] = f2b(acc[qt][dt][g] / denom);
        }
    }
}

// ---------------------------------------------------------------------------
// Glue kernels.
__global__ void concat2_k(u16* __restrict__ dst, const u16* __restrict__ s0,
                          const u16* __restrict__ s1, int total) {
    int i = blockIdx.x * 256 + threadIdx.x;
    if (i >= total) return;
    int j = i & 1023;
    int t = i >> 10;
    int seg = t & 1;
    int n = t >> 1;
    const u16* s = seg ? s1 : s0;
    dst[i] = s[(size_t)n * 1024 + j];
}

// cu_in = concat([connection(fp32), z1(bf16), dz(bf16)], -1)
__global__ void cucat_k(u16* __restrict__ dst, const float* __restrict__ conn,
                        const u16* __restrict__ z1, const u16* __restrict__ dz,
                        int total) {
    int i = blockIdx.x * 256 + threadIdx.x;
    if (i >= total) return;
    int j = i & 1023;
    int t = i >> 10;
    int seg = t % 3;
    int n = t / 3;
    size_t src = (size_t)n * 1024 + j;
    dst[i] = (seg == 0) ? f2b(conn[src]) : (seg == 1 ? z1[src] : dz[src]);
}

__global__ void dz_k(u16* __restrict__ d, const u16* __restrict__ a,
                     const u16* __restrict__ b, const float* __restrict__ dtp, int n) {
    int i = blockIdx.x * 256 + threadIdx.x;
    if (i >= n) return;
    float dt = dtp[0];
    d[i] = f2b(dt * (b2f(a[i]) + b2f(b[i])));
}

// z1 = z(fp32) + dz(bf16) + ctx(bf16) -> bf16 internal
__global__ void z1_k(u16* __restrict__ d, const float* __restrict__ z,
                     const u16* __restrict__ dz, const u16* __restrict__ ctx, int n) {
    int i = blockIdx.x * 256 + threadIdx.x;
    if (i >= n) return;
    d[i] = f2b(z[i] + b2f(dz[i]) + b2f(ctx[i]));
}

// conn_new = connection(fp32) + delta(bf16) -> fp32 out
__global__ void connew_k(float* __restrict__ d, const float* __restrict__ conn,
                         const u16* __restrict__ delta, int n) {
    int i = blockIdx.x * 256 + threadIdx.x;
    if (i >= n) return;
    d[i] = conn[i] + b2f(delta[i]);
}

// z2 = z1(bf16) + mf(bf16) -> fp32 out
__global__ void z2_k(float* __restrict__ d, const u16* __restrict__ z1,
                     const u16* __restrict__ mf, int n) {
    int i = blockIdx.x * 256 + threadIdx.x;
    if (i >= n) return;
    d[i] = b2f(z1[i]) + b2f(mf[i]);
}

__global__ void copyf_k(float* __restrict__ d, const float* __restrict__ s, int n) {
    int i = (blockIdx.x * 256 + threadIdx.x) * 4;
    if (i >= n) return;
    *(float4*)(d + i) = *(const float4*)(s + i);
}

// ---------------------------------------------------------------------------
extern "C" void kernel_launch(void* const* d_in, const int* in_sizes, int n_in,
                              void* d_out, int out_size, void* d_ws, size_t ws_size,
                              hipStream_t stream) {
    const int B = 2, L = 2048, D = 1024, H = 16, N = B * L;
    const float* z      = (const float*)d_in[0];
    const float* conn   = (const float*)d_in[1];
    const float* w_z    = (const float*)d_in[2];
    const float* w_c    = (const float*)d_in[3];
    const float* w_mlp  = (const float*)d_in[4];
    const float* f_w1   = (const float*)d_in[5];
    const float* f_b1   = (const float*)d_in[6];
    const float* f_w2   = (const float*)d_in[7];
    const float* f_b2   = (const float*)d_in[8];
    const float* g_w1   = (const float*)d_in[9];
    const float* g_b1   = (const float*)d_in[10];
    const float* g_w2   = (const float*)d_in[11];
    const float* g_b2   = (const float*)d_in[12];
    const float* dt_p   = (const float*)d_in[13];
    const float* q_w    = (const float*)d_in[14];
    const float* k_w    = (const float*)d_in[15];
    const float* v_w    = (const float*)d_in[16];
    const float* o_w    = (const float*)d_in[17];
    const float* temp_p = (const float*)d_in[18];
    const float* cu_w1  = (const float*)d_in[19];
    const float* cu_b1  = (const float*)d_in[20];
    const float* cu_w2  = (const float*)d_in[21];
    const float* cu_b2  = (const float*)d_in[22];
    const float* m_w1   = (const float*)d_in[23];
    const float* m_b1   = (const float*)d_in[24];
    const float* m_w2   = (const float*)d_in[25];
    const float* m_b2   = (const float*)d_in[26];

    float* out = (float*)d_out;
    u16* ws  = (u16*)d_ws;
    const size_t U = (size_t)N * D;   // 4M elems

    // Activation slots (bf16), liveness-packed: peak slot index 8 (9 units).
    u16* zn    = ws + 0 * U;
    u16* cn    = ws + 1 * U;
    u16* h1    = ws + 2 * U;   // 2 units (2-3)
    u16* dzl   = ws + 4 * U;
    u16* gcat  = ws + 5 * U;   // 2 units (5-6)
    u16* gh    = ws + 7 * U;
    u16* corr  = ws + 5 * U;   // gcat dead
    u16* dz    = ws + 6 * U;
    u16* zc    = ws + 2 * U;   // 2 units (2-3), h1 dead
    u16* Qb    = ws + 4 * U;   // dzl dead
    u16* Kbuf  = ws + 5 * U;   // corr dead
    u16* VT    = ws + 7 * U;   // gh dead; VT[bh][64][L], 4M elems
    u16* attn  = ws + 8 * U;
    u16* ctx   = ws + 4 * U;   // Qb dead
    u16* z1    = ws + 5 * U;   // Kbuf dead
    u16* cu_in = ws + 0 * U;   // 3 units (0-2): zn,cn,zc dead
    u16* cu_h  = ws + 3 * U;   // 2 units (3-4): zc(3),ctx dead
    u16* delta = ws + 7 * U;   // VT dead
    u16* z1n   = ws + 0 * U;   // cu_in dead
    u16* mh    = ws + 1 * U;   // 4 units (1-4)
    u16* mf    = ws + 0 * U;   // z1n dead

    // bf16 weight copies after activation slots: 29M u16 elems.
    u16* wb = ws + 9 * U;
    u16* bf_w1  = wb + 0;                       // 2M
    u16* bf_w2  = wb + 2 * 1024 * 1024;         // 2M
    u16* bg_w1  = wb + 4 * 1024 * 1024;         // 2M
    u16* bg_w2  = wb + 6 * 1024 * 1024;         // 1M
    u16* bq_w   = wb + 7 * 1024 * 1024;         // 2M
    u16* bk_w   = wb + 9 * 1024 * 1024;         // 2M
    u16* bv_w   = wb + 11 * 1024 * 1024;        // 1M
    u16* bo_w   = wb + 12 * 1024 * 1024;        // 1M
    u16* bcu_w1 = wb + 13 * 1024 * 1024;        // 6M
    u16* bcu_w2 = wb + 19 * 1024 * 1024;        // 2M
    u16* bm_w1  = wb + 21 * 1024 * 1024;        // 4M
    u16* bm_w2  = wb + 25 * 1024 * 1024;        // 4M

    auto cvt = [&](const float* s, u16* d, int n) {
        cvt_k<<<n / 1024, 256, 0, stream>>>(s, d, n);
    };
    cvt(f_w1, bf_w1, 2 * D * D);   cvt(f_w2, bf_w2, 2 * D * D);
    cvt(g_w1, bg_w1, 2 * D * D);   cvt(g_w2, bg_w2, D * D);
    cvt(q_w, bq_w, 2 * D * D);     cvt(k_w, bk_w, 2 * D * D);
    cvt(v_w, bv_w, D * D);         cvt(o_w, bo_w, D * D);
    cvt(cu_w1, bcu_w1, 6 * D * D); cvt(cu_w2, bcu_w2, 2 * D * D);
    cvt(m_w1, bm_w1, 4 * D * D);   cvt(m_w2, bm_w2, 4 * D * D);

    const int EW = (N * D + 255) / 256;
    auto gemm = [&](const u16* A, const u16* W, const float* bias, u16* C,
                    int K, int O, int act, int mode = 0) {
        dim3 grid(O / 128, N / 128);
        gemm_tile<<<grid, 256, 0, stream>>>(A, W, bias, C, K, O, act, mode);
    };

    rmsf_k<<<N, 256, 0, stream>>>(z, w_z, zn, D);
    rmsf_k<<<N, 256, 0, stream>>>(conn, w_c, cn, D);

    gemm(zn, bf_w1, f_b1, h1, D, 2 * D, 1);                  // silu
    gemm(h1, bf_w2, f_b2, dzl, 2 * D, D, 0);
    concat2_k<<<(N * 2 * D + 255) / 256, 256, 0, stream>>>(gcat, cn, dzl, N * 2 * D);
    gemm(gcat, bg_w1, g_b1, gh, 2 * D, D, 2);                // tanh
    gemm(gh, bg_w2, g_b2, corr, D, D, 0);
    dz_k<<<EW, 256, 0, stream>>>(dz, dzl, corr, dt_p, N * D);

    concat2_k<<<(N * 2 * D + 255) / 256, 256, 0, stream>>>(zc, zn, cn, N * 2 * D);
    gemm(zc, bq_w, nullptr, Qb, 2 * D, D, 0);
    gemm(zc, bk_w, nullptr, Kbuf, 2 * D, D, 0);
    gemm(zn, bv_w, nullptr, VT, D, D, 0, 1);                 // V, transposed per head
    attn_k<<<B * H * L / 128, 256, 0, stream>>>(Qb, Kbuf, VT, temp_p, attn);
    gemm(attn, bo_w, nullptr, ctx, D, D, 0);

    z1_k<<<EW, 256, 0, stream>>>(z1, z, dz, ctx, N * D);

    cucat_k<<<(N * 3 * D + 255) / 256, 256, 0, stream>>>(cu_in, conn, z1, dz, N * 3 * D);
    gemm(cu_in, bcu_w1, cu_b1, cu_h, 3 * D, 2 * D, 1);       // silu
    gemm(cu_h, bcu_w2, cu_b2, delta, 2 * D, D, 0);
    connew_k<<<EW, 256, 0, stream>>>(out + U, conn, delta, N * D);   // conn_new
    copyf_k<<<(N * D + 1023) / 1024, 256, 0, stream>>>(out + 2 * U, z, N * D); // z_before

    rmsb_k<<<N, 256, 0, stream>>>(z1, w_mlp, z1n, D);
    gemm(z1n, bm_w1, m_b1, mh, D, 4 * D, 1);                 // silu
    gemm(mh, bm_w2, m_b2, mf, 4 * D, D, 0);
    z2_k<<<EW, 256, 0, stream>>>(out, z1, mf, N * D);                // z2
}